// Round 3
// baseline (276.572 us; speedup 1.0000x reference)
//
#include <hip/hip_runtime.h>

#define EPS 1e-3f

// x: [16,56,56,128], out: [16,28,28,256], G=32 groups, BF=4
#define NPIX   50176   // 16*56*56
#define NOPIX  12544   // 16*28*28

// ws float offsets
#define OFF_ST1  0        // [32][128][2] interleaved (s,t) for bn1
#define OFF_S2   8192     // [32][4]
#define OFF_T2   8320
#define OFF_T3   8576
#define OFF_BSUM 8704     // [256]
#define OFF_W3S  8960     // [32][144] W3 pre-scaled by s3
#define OFF_U    13568    // U stored GROUP-MAJOR: [32][NPIX][4] fp32

__global__ __launch_bounds__(256)
void prep_kernel(const float* __restrict__ g1, const float* __restrict__ be1,
                 const float* __restrict__ m1, const float* __restrict__ v1,
                 const float* __restrict__ b1, const float* __restrict__ g2,
                 const float* __restrict__ be2, const float* __restrict__ m2,
                 const float* __restrict__ v2, const float* __restrict__ W3,
                 const float* __restrict__ b3, const float* __restrict__ g3,
                 const float* __restrict__ be3, const float* __restrict__ m3,
                 const float* __restrict__ v3, const float* __restrict__ b2,
                 float* __restrict__ ws) {
    int gid = blockIdx.x * 256 + threadIdx.x;
    int stride = gridDim.x * 256;
    for (int i = gid; i < 4096; i += stride) {
        float s = g1[i] * rsqrtf(v1[i] + EPS);
        float t = be1[i] - m1[i] * s;
        ws[OFF_ST1 + 2*i]     = s;
        ws[OFF_ST1 + 2*i + 1] = t;
    }
    for (int i = gid; i < 4608; i += stride) {
        int g = i / 144;
        int f = i & 3;
        int k = g*4 + f;
        float s3 = g3[k] * rsqrtf(v3[k] + EPS);
        ws[OFF_W3S + i] = W3[i] * s3;
    }
    if (gid < 128) {
        float s2 = g2[gid] * rsqrtf(v2[gid] + EPS);
        ws[OFF_S2 + gid] = s2;
        ws[OFF_T2 + gid] = be2[gid] + (b1[gid] - m2[gid]) * s2;
        float s3 = g3[gid] * rsqrtf(v3[gid] + EPS);
        ws[OFF_T3 + gid] = be3[gid] + (b3[gid] - m3[gid]) * s3;
    } else if (gid >= 256 && gid < 512) {
        int co = gid - 256;
        float acc = 0.f;
        for (int g = 0; g < 32; ++g) acc += b2[g*256 + co];
        ws[OFF_BSUM + co] = acc;
    }
}

// Stage 1: U[g][px][f] = relu(s2*(sum_c relu(x*s1+t1)*W1) + t2)
// block = 256 thr = 4 waves; wave = 64 px, each wave does 8 groups (uniform g
// -> scalar table loads). x cached in registers per 32-channel chunk.
// Writes are group-major -> each wave store is a 1 KB coalesced burst.
__global__ __launch_bounds__(256)
void stage1_kernel(const float* __restrict__ x,
                   const float* __restrict__ W1,     // [32,128,4]
                   const float* __restrict__ tabs,   // ws
                   float* __restrict__ uout) {       // ws + OFF_U
    __shared__ float xs[64 * 132];
    int tid = threadIdx.x;
    const float4* x4 = (const float4*)x + (size_t)blockIdx.x * 2048;
    for (int i = tid; i < 2048; i += 256) {
        float4 v = x4[i];
        int p = i >> 5, c4 = (i & 31) << 2;
        *(float4*)(xs + p * 132 + c4) = v;
    }
    __syncthreads();

    int lane = tid & 63;
    int gbase = __builtin_amdgcn_readfirstlane(tid >> 6) * 8;
    const float* xp = xs + lane * 132;

    float acc[8][4];
    #pragma unroll
    for (int gi = 0; gi < 8; ++gi)
        #pragma unroll
        for (int f = 0; f < 4; ++f) acc[gi][f] = 0.f;

    for (int chunk = 0; chunk < 4; ++chunk) {   // real loop: keep I-cache sane
        float xr[32];
        #pragma unroll
        for (int j = 0; j < 8; ++j)
            *(float4*)&xr[j*4] = *(const float4*)(xp + chunk*32 + j*4);
        #pragma unroll
        for (int gi = 0; gi < 8; ++gi) {
            int g = gbase + gi;
            const float2* st = (const float2*)(tabs + OFF_ST1) + g*128 + chunk*32;
            const float4* w1 = (const float4*)W1 + g*128 + chunk*32;
            #pragma unroll 8
            for (int c = 0; c < 32; ++c) {
                float2 s = st[c];          // uniform -> s_load
                float4 w = w1[c];          // uniform -> s_load
                float z = fmaxf(fmaf(xr[c], s.x, s.y), 0.f);
                acc[gi][0] = fmaf(z, w.x, acc[gi][0]);
                acc[gi][1] = fmaf(z, w.y, acc[gi][1]);
                acc[gi][2] = fmaf(z, w.z, acc[gi][2]);
                acc[gi][3] = fmaf(z, w.w, acc[gi][3]);
            }
        }
    }

    size_t pxIdx = (size_t)blockIdx.x * 64 + lane;
    float4* U4 = (float4*)uout;
    #pragma unroll
    for (int gi = 0; gi < 8; ++gi) {
        int g = gbase + gi;
        float4 s2v = ((const float4*)(tabs + OFF_S2))[g];
        float4 t2v = ((const float4*)(tabs + OFF_T2))[g];
        float4 u;
        u.x = fmaxf(fmaf(acc[gi][0], s2v.x, t2v.x), 0.f);
        u.y = fmaxf(fmaf(acc[gi][1], s2v.y, t2v.y), 0.f);
        u.z = fmaxf(fmaf(acc[gi][2], s2v.z, t2v.z), 0.f);
        u.w = fmaxf(fmaf(acc[gi][3], s2v.w, t2v.w), 0.f);
        U4[(size_t)g * NPIX + pxIdx] = u;   // 64 lanes consecutive: 1 KB burst
    }
}

// Stage 2: 3x3 s2 conv (+bn3/relu) -> vs[8][128]; out = vs @ W2 + bsum + res
// block = 256 threads, 8 output pixels. U is group-major now.
__global__ __launch_bounds__(256)
void stage2_kernel(const float* __restrict__ x,
                   const float* __restrict__ W2,     // [128,256]
                   const float* __restrict__ tabs,   // ws
                   const float* __restrict__ U,      // ws + OFF_U (group-major)
                   float* __restrict__ out) {
    __shared__ float w3s[32 * 145];  // stride 145 -> conflict-free across g
    __shared__ float vs[8 * 128];
    __shared__ float res_s[8];
    int tid = threadIdx.x;
    for (int i = tid; i < 4608; i += 256) {
        int g = i / 144, idx = i - g * 144;
        w3s[g * 145 + idx] = tabs[OFF_W3S + i];
    }
    __syncthreads();

    int opBase = blockIdx.x * 8;
    int p = tid >> 5, g = tid & 31;
    int op = opBase + p;
    int b = op / 784;
    int r = op - b * 784;
    int oh = r / 28;
    int ow = r - oh * 28;

    // ---- phase A: 3x3 stride-2 conv for this (pixel, group) ----
    {
        const float4* Ug = (const float4*)U + (size_t)g * NPIX;
        const float* wg = w3s + g * 145;
        float a0 = 0.f, a1 = 0.f, a2 = 0.f, a3 = 0.f;
        #pragma unroll
        for (int kh = 0; kh < 3; ++kh) {
            int ih = 2*oh - 1 + kh;
            if (ih < 0) continue;
            #pragma unroll
            for (int kw = 0; kw < 3; ++kw) {
                int iw = 2*ow - 1 + kw;
                if (iw < 0) continue;
                float4 u = Ug[(size_t)(b*56 + ih)*56 + iw];
                const float* wk = wg + (kh*3 + kw) * 16;
                a0 = fmaf(u.x, wk[0],  a0); a1 = fmaf(u.x, wk[1],  a1);
                a2 = fmaf(u.x, wk[2],  a2); a3 = fmaf(u.x, wk[3],  a3);
                a0 = fmaf(u.y, wk[4],  a0); a1 = fmaf(u.y, wk[5],  a1);
                a2 = fmaf(u.y, wk[6],  a2); a3 = fmaf(u.y, wk[7],  a3);
                a0 = fmaf(u.z, wk[8],  a0); a1 = fmaf(u.z, wk[9],  a1);
                a2 = fmaf(u.z, wk[10], a2); a3 = fmaf(u.z, wk[11], a3);
                a0 = fmaf(u.w, wk[12], a0); a1 = fmaf(u.w, wk[13], a1);
                a2 = fmaf(u.w, wk[14], a2); a3 = fmaf(u.w, wk[15], a3);
            }
        }
        float4 t3v = ((const float4*)(tabs + OFF_T3))[g];
        float4 v;
        v.x = fmaxf(a0 + t3v.x, 0.f);
        v.y = fmaxf(a1 + t3v.y, 0.f);
        v.z = fmaxf(a2 + t3v.z, 0.f);
        v.w = fmaxf(a3 + t3v.w, 0.f);
        ((float4*)vs)[p * 32 + g] = v;
    }
    // ---- residual: res[p] = sum_c x[b, 2oh, 2ow, c] ----
    {
        const float* xp = x + ((size_t)(b*56 + 2*oh)*56 + 2*ow) * 128;
        float v = xp[g] + xp[g+32] + xp[g+64] + xp[g+96];
        for (int off = 16; off; off >>= 1) v += __shfl_down(v, off, 32);
        if (g == 0) res_s[p] = v;
    }
    __syncthreads();

    // ---- phase B: out[op, co] = sum_k vs[p][k]*W2[k][co] + bsum + res ----
    int co = tid;
    float bs = tabs[OFF_BSUM + co];
    float acc[8];
    #pragma unroll
    for (int q = 0; q < 8; ++q) acc[q] = bs;
    const float4* vs4 = (const float4*)vs;
    #pragma unroll 4
    for (int k4 = 0; k4 < 32; ++k4) {
        float w0 = W2[(4*k4+0)*256 + co];
        float w1 = W2[(4*k4+1)*256 + co];
        float w2 = W2[(4*k4+2)*256 + co];
        float w3 = W2[(4*k4+3)*256 + co];
        #pragma unroll
        for (int q = 0; q < 8; ++q) {
            float4 v = vs4[q*32 + k4];
            acc[q] = fmaf(v.x, w0, acc[q]);
            acc[q] = fmaf(v.y, w1, acc[q]);
            acc[q] = fmaf(v.z, w2, acc[q]);
            acc[q] = fmaf(v.w, w3, acc[q]);
        }
    }
    #pragma unroll
    for (int q = 0; q < 8; ++q)
        out[(size_t)(opBase + q) * 256 + co] = acc[q] + res_s[q];
}

extern "C" void kernel_launch(void* const* d_in, const int* in_sizes, int n_in,
                              void* d_out, int out_size, void* d_ws, size_t ws_size,
                              hipStream_t stream) {
    const float* x   = (const float*)d_in[0];
    const float* g1  = (const float*)d_in[1];
    const float* be1 = (const float*)d_in[2];
    const float* m1  = (const float*)d_in[3];
    const float* v1  = (const float*)d_in[4];
    const float* W1  = (const float*)d_in[5];
    const float* b1  = (const float*)d_in[6];
    const float* g2  = (const float*)d_in[7];
    const float* be2 = (const float*)d_in[8];
    const float* m2  = (const float*)d_in[9];
    const float* v2  = (const float*)d_in[10];
    const float* W3  = (const float*)d_in[11];
    const float* b3  = (const float*)d_in[12];
    const float* g3  = (const float*)d_in[13];
    const float* be3 = (const float*)d_in[14];
    const float* m3  = (const float*)d_in[15];
    const float* v3  = (const float*)d_in[16];
    const float* W2  = (const float*)d_in[17];
    const float* b2  = (const float*)d_in[18];
    float* out = (float*)d_out;
    float* ws  = (float*)d_ws;

    prep_kernel<<<32, 256, 0, stream>>>(g1, be1, m1, v1, b1, g2, be2, m2, v2,
                                        W3, b3, g3, be3, m3, v3, b2, ws);
    stage1_kernel<<<NPIX / 64, 256, 0, stream>>>(x, W1, ws, ws + OFF_U);
    stage2_kernel<<<NOPIX / 8, 256, 0, stream>>>(x, W2, ws, ws + OFF_U, out);
}